// Round 2
// baseline (1419.888 us; speedup 1.0000x reference)
//
#include <hip/hip_runtime.h>
#include <hip/hip_bf16.h>

#define LEAKY 0.2f

// ---------------- CSR build ----------------

__global__ __launch_bounds__(256) void k_init(int* cnt, int* bstart, int n, int nb) {
    int i = blockIdx.x * 256 + threadIdx.x;
    if (i < n) cnt[i] = 1;            // self-loop pre-counted
    if (i < nb) bstart[i] = n;        // batch-boundary init
}

__global__ __launch_bounds__(256) void k_count(const int* __restrict__ dst, int* cnt, int e) {
    int i = blockIdx.x * 256 + threadIdx.x;
    if (i < e) atomicAdd(&cnt[dst[i]], 1);
}

// single-block scan: 8 elems/thread, wave shfl scan, cross-wave via LDS
__global__ __launch_bounds__(1024) void k_scan(const int* __restrict__ cnt, int* row_ptr, int n) {
    __shared__ int wsum[17];  // 16 wave totals + running carry
    int tid = threadIdx.x, lane = tid & 63, wid = tid >> 6;
    if (tid == 0) { wsum[16] = 0; row_ptr[0] = 0; }
    __syncthreads();
    for (int base = 0; base < n; base += 8192) {
        int i0 = base + tid * 8;
        int v, p = 0, pref[8];
#pragma unroll
        for (int j = 0; j < 8; ++j) {
            int idx = i0 + j;
            v = (idx < n) ? cnt[idx] : 0;
            p += v; pref[j] = p;
        }
        int sc = p;
#pragma unroll
        for (int o = 1; o < 64; o <<= 1) { int t = __shfl_up(sc, o); if (lane >= o) sc += t; }
        if (lane == 63) wsum[wid] = sc;
        __syncthreads();
        if (tid == 0) {
            int run = wsum[16];
            for (int ww = 0; ww < 16; ++ww) { int tt = wsum[ww]; wsum[ww] = run; run += tt; }
            wsum[16] = run;
        }
        __syncthreads();
        int off = wsum[wid] + (sc - p);  // exclusive prefix for this thread
#pragma unroll
        for (int j = 0; j < 8; ++j) {
            int idx = i0 + j;
            if (idx < n) row_ptr[idx + 1] = off + pref[j];
        }
        __syncthreads();
    }
}

__global__ __launch_bounds__(256) void k_selfloop(const int* __restrict__ row_ptr, int* csr, int* cursor, int n) {
    int i = blockIdx.x * 256 + threadIdx.x;
    if (i < n) { int p = row_ptr[i]; csr[p] = i; cursor[i] = p + 1; }
}

__global__ __launch_bounds__(256) void k_scatter(const int* __restrict__ src, const int* __restrict__ dst,
                                                 int* cursor, int* csr, int e) {
    int i = blockIdx.x * 256 + threadIdx.x;
    if (i < e) { int p = atomicAdd(&cursor[dst[i]], 1); csr[p] = src[i]; }
}

__global__ __launch_bounds__(256) void k_bbounds(const int* __restrict__ bidx, int* bstart, int n) {
    int i = blockIdx.x * 256 + threadIdx.x;
    if (i < n) {
        int b = bidx[i];
        if (i == 0 || bidx[i - 1] != b) atomicMin(&bstart[b], i);
    }
}

__global__ void k_bfix(int* bstart, int n, int nb) {
    bstart[nb] = n;
    for (int b = nb - 1; b >= 0; --b)
        if (bstart[b] == n) bstart[b] = bstart[b + 1];
}

// ---------------- GEMM: C[nrows x 128] = A[nrows x 128] @ W[128 x 128] ----------------
// block: 256 threads, 64 rows/block; thread: 2 rows x 16 cols (cols tx*4+g*32)
__global__ __launch_bounds__(256) void k_gemm(const float* __restrict__ A, const float* __restrict__ W,
                                              float* __restrict__ C, int nrows) {
    __shared__ float Wl[128 * 128];
    int tid = threadIdx.x;
    for (int i = tid * 4; i < 128 * 128; i += 1024)
        *(float4*)&Wl[i] = *(const float4*)&W[i];
    __syncthreads();

    int ty = tid >> 3, tx = tid & 7;
    int row0 = blockIdx.x * 64 + ty * 2;
    int r0 = min(row0, nrows - 1);
    int r1 = min(row0 + 1, nrows - 1);
    const float* A0 = A + (size_t)r0 * 128;
    const float* A1 = A + (size_t)r1 * 128;

    float acc0[16], acc1[16];
#pragma unroll
    for (int i = 0; i < 16; ++i) { acc0[i] = 0.f; acc1[i] = 0.f; }

    for (int k0 = 0; k0 < 128; k0 += 8) {
        float a0v[8], a1v[8];
        *(float4*)&a0v[0] = *(const float4*)&A0[k0];
        *(float4*)&a0v[4] = *(const float4*)&A0[k0 + 4];
        *(float4*)&a1v[0] = *(const float4*)&A1[k0];
        *(float4*)&a1v[4] = *(const float4*)&A1[k0 + 4];
#pragma unroll
        for (int kk = 0; kk < 8; ++kk) {
#pragma unroll
            for (int g = 0; g < 4; ++g) {
                float4 w = *(float4*)&Wl[(k0 + kk) * 128 + tx * 4 + g * 32];
                acc0[g * 4 + 0] = fmaf(a0v[kk], w.x, acc0[g * 4 + 0]);
                acc0[g * 4 + 1] = fmaf(a0v[kk], w.y, acc0[g * 4 + 1]);
                acc0[g * 4 + 2] = fmaf(a0v[kk], w.z, acc0[g * 4 + 2]);
                acc0[g * 4 + 3] = fmaf(a0v[kk], w.w, acc0[g * 4 + 3]);
                acc1[g * 4 + 0] = fmaf(a1v[kk], w.x, acc1[g * 4 + 0]);
                acc1[g * 4 + 1] = fmaf(a1v[kk], w.y, acc1[g * 4 + 1]);
                acc1[g * 4 + 2] = fmaf(a1v[kk], w.z, acc1[g * 4 + 2]);
                acc1[g * 4 + 3] = fmaf(a1v[kk], w.w, acc1[g * 4 + 3]);
            }
        }
    }
    if (row0 < nrows) {
#pragma unroll
        for (int g = 0; g < 4; ++g)
            *(float4*)&C[(size_t)row0 * 128 + tx * 4 + g * 32] =
                make_float4(acc0[g * 4], acc0[g * 4 + 1], acc0[g * 4 + 2], acc0[g * 4 + 3]);
    }
    if (row0 + 1 < nrows) {
#pragma unroll
        for (int g = 0; g < 4; ++g)
            *(float4*)&C[(size_t)(row0 + 1) * 128 + tx * 4 + g * 32] =
                make_float4(acc1[g * 4], acc1[g * 4 + 1], acc1[g * 4 + 2], acc1[g * 4 + 3]);
    }
}

// ---------------- per-node attention logits ----------------
__global__ __launch_bounds__(256) void k_alpha(const float* __restrict__ h, const float* __restrict__ asrc,
                                               const float* __restrict__ adst, float* vas, float* vad, int n) {
    int w = (blockIdx.x * 256 + threadIdx.x) >> 6;
    int lane = threadIdx.x & 63;
    if (w >= n) return;
    float h0 = h[(size_t)w * 128 + lane];
    float h1 = h[(size_t)w * 128 + lane + 64];
    float s = h0 * asrc[lane] + h1 * asrc[lane + 64];
    float d = h0 * adst[lane] + h1 * adst[lane + 64];
#pragma unroll
    for (int o = 32; o; o >>= 1) { s += __shfl_xor(s, o); d += __shfl_xor(d, o); }
    if (lane == 0) { vas[w] = s; vad[w] = d; }
}

// ---------------- aggregation: one wave per dst node ----------------
template <bool RELU>
__global__ __launch_bounds__(256) void k_agg(const float* __restrict__ h, const float* __restrict__ vas,
                                             const float* __restrict__ vad, const int* __restrict__ row_ptr,
                                             const int* __restrict__ csr, const float* __restrict__ bias,
                                             float* __restrict__ out, int n) {
    int w = (blockIdx.x * 256 + threadIdx.x) >> 6;
    int lane = threadIdx.x & 63;
    if (w >= n) return;
    int beg = row_ptr[w], end = row_ptr[w + 1];
    float advl = vad[w];

    float m = -1e30f;
    for (int j = beg + lane; j < end; j += 64) {
        float e = vas[csr[j]] + advl;
        e = e > 0.f ? e : LEAKY * e;
        m = fmaxf(m, e);
    }
#pragma unroll
    for (int o = 32; o; o >>= 1) m = fmaxf(m, __shfl_xor(m, o));

    float z = 0.f;
    for (int j = beg + lane; j < end; j += 64) {
        float e = vas[csr[j]] + advl;
        e = e > 0.f ? e : LEAKY * e;
        z += __expf(e - m);
    }
#pragma unroll
    for (int o = 32; o; o >>= 1) z += __shfl_xor(z, o);
    float inv = 1.0f / z;

    float acc0 = 0.f, acc1 = 0.f;
    for (int j = beg; j < end; ++j) {
        int s = csr[j];
        float e = vas[s] + advl;
        e = e > 0.f ? e : LEAKY * e;
        float wgt = __expf(e - m) * inv;
        acc0 = fmaf(wgt, h[(size_t)s * 128 + lane], acc0);
        acc1 = fmaf(wgt, h[(size_t)s * 128 + lane + 64], acc1);
    }
    float v0 = acc0 + bias[lane];
    float v1 = acc1 + bias[lane + 64];
    if (RELU) { v0 = fmaxf(v0, 0.f); v1 = fmaxf(v1, 0.f); }
    out[(size_t)w * 128 + lane] = v0;
    out[(size_t)w * 128 + lane + 64] = v1;
}

// ---------------- batch mean pool (batch_idx sorted) ----------------
__global__ __launch_bounds__(128) void k_pool(const float* __restrict__ h, const int* __restrict__ bstart,
                                              float* __restrict__ out, int t, int T) {
    int b = blockIdx.x;
    int chunk = blockIdx.y;
    int f = threadIdx.x;
    int s = bstart[b], e = bstart[b + 1];
    int cnt = e - s;
    if (cnt <= 0) return;
    int len = (cnt + 31) / 32;
    int cs = s + chunk * len;
    int ce = min(cs + len, e);
    if (cs >= ce) return;
    float acc = 0.f;
    for (int nidx = cs; nidx < ce; ++nidx) acc += h[(size_t)nidx * 128 + f];
    atomicAdd(&out[(size_t)(b * T + t) * 128 + f], acc / (float)cnt);
}

// ---------------- launch ----------------

extern "C" void kernel_launch(void* const* d_in, const int* in_sizes, int n_in,
                              void* d_out, int out_size, void* d_ws, size_t ws_size,
                              hipStream_t stream) {
    const float* x    = (const float*)d_in[0];
    const int*   ei   = (const int*)d_in[1];
    const int*   bidx = (const int*)d_in[2];
    const float* W1   = (const float*)d_in[3];
    const float* as1  = (const float*)d_in[4];
    const float* ad1  = (const float*)d_in[5];
    const float* b1   = (const float*)d_in[6];
    const float* W2   = (const float*)d_in[7];
    const float* as2  = (const float*)d_in[8];
    const float* ad2  = (const float*)d_in[9];
    const float* b2   = (const float*)d_in[10];
    float* out = (float*)d_out;

    const int E = in_sizes[1] / 2;
    const int N = in_sizes[2];
    const int T = in_sizes[0] / (N * 128);
    const int B = out_size / (T * 128);
    const int* src = ei;
    const int* dst = ei + E;

    char* wsp = (char*)d_ws;
    auto alloc = [&](size_t bytes) { void* p = wsp; wsp += (bytes + 255) / 256 * 256; return p; };
    float* bufA   = (float*)alloc((size_t)N * 128 * 4);
    float* bufB   = (float*)alloc((size_t)N * 128 * 4);
    float* vas    = (float*)alloc((size_t)N * 4);
    float* vad    = (float*)alloc((size_t)N * 4);
    int* row_ptr  = (int*)alloc((size_t)(N + 1) * 4);
    int* cnt      = (int*)alloc((size_t)N * 4);   // reused as scatter cursor
    int* csr      = (int*)alloc((size_t)(E + N) * 4);
    int* bstart   = (int*)alloc((size_t)(B + 2) * 4);

    hipMemsetAsync(d_out, 0, (size_t)out_size * sizeof(float), stream);

    int gN = (N + 255) / 256, gE = (E + 255) / 256;
    k_init<<<gN, 256, 0, stream>>>(cnt, bstart, N, B + 1);
    k_count<<<gE, 256, 0, stream>>>(dst, cnt, E);
    k_scan<<<1, 1024, 0, stream>>>(cnt, row_ptr, N);
    k_selfloop<<<gN, 256, 0, stream>>>(row_ptr, csr, cnt, N);
    k_scatter<<<gE, 256, 0, stream>>>(src, dst, cnt, csr, E);
    k_bbounds<<<gN, 256, 0, stream>>>(bidx, bstart, N);
    k_bfix<<<1, 1, 0, stream>>>(bstart, N, B);

    int gGemm = (N + 63) / 64;
    int gWave = (N + 3) / 4;  // 4 waves (nodes) per 256-thread block
    for (int t = 0; t < T; ++t) {
        const float* xt = x + (size_t)t * N * 128;
        k_gemm<<<gGemm, 256, 0, stream>>>(xt, W1, bufA, N);
        k_alpha<<<gWave, 256, 0, stream>>>(bufA, as1, ad1, vas, vad, N);
        k_agg<true><<<gWave, 256, 0, stream>>>(bufA, vas, vad, row_ptr, csr, b1, bufB, N);
        k_gemm<<<gGemm, 256, 0, stream>>>(bufB, W2, bufA, N);
        k_alpha<<<gWave, 256, 0, stream>>>(bufA, as2, ad2, vas, vad, N);
        k_agg<false><<<gWave, 256, 0, stream>>>(bufA, vas, vad, row_ptr, csr, b2, bufB, N);
        k_pool<<<dim3(B, 32), 128, 0, stream>>>(bufB, bstart, out, t, T);
    }
}

// Round 3
// 1100.507 us; speedup vs baseline: 1.2902x; 1.2902x over previous
//
#include <hip/hip_runtime.h>
#include <hip/hip_bf16.h>

#define LEAKY 0.2f

// ---------------- CSR build ----------------

__global__ __launch_bounds__(256) void k_init(int* cnt, int* bstart, int n, int nb) {
    int i = blockIdx.x * 256 + threadIdx.x;
    if (i < n) cnt[i] = 1;            // self-loop pre-counted
    if (i < nb) bstart[i] = n;        // batch-boundary init
}

__global__ __launch_bounds__(256) void k_count(const int* __restrict__ dst, int* cnt, int e) {
    int i = blockIdx.x * 256 + threadIdx.x;
    if (i < e) atomicAdd(&cnt[dst[i]], 1);
}

// single-block scan: 8 elems/thread, wave shfl scan, cross-wave via LDS
__global__ __launch_bounds__(1024) void k_scan(const int* __restrict__ cnt, int* row_ptr, int n) {
    __shared__ int wsum[17];
    int tid = threadIdx.x, lane = tid & 63, wid = tid >> 6;
    if (tid == 0) { wsum[16] = 0; row_ptr[0] = 0; }
    __syncthreads();
    for (int base = 0; base < n; base += 8192) {
        int i0 = base + tid * 8;
        int v, p = 0, pref[8];
#pragma unroll
        for (int j = 0; j < 8; ++j) {
            int idx = i0 + j;
            v = (idx < n) ? cnt[idx] : 0;
            p += v; pref[j] = p;
        }
        int sc = p;
#pragma unroll
        for (int o = 1; o < 64; o <<= 1) { int t = __shfl_up(sc, o); if (lane >= o) sc += t; }
        if (lane == 63) wsum[wid] = sc;
        __syncthreads();
        if (tid == 0) {
            int run = wsum[16];
            for (int ww = 0; ww < 16; ++ww) { int tt = wsum[ww]; wsum[ww] = run; run += tt; }
            wsum[16] = run;
        }
        __syncthreads();
        int off = wsum[wid] + (sc - p);
#pragma unroll
        for (int j = 0; j < 8; ++j) {
            int idx = i0 + j;
            if (idx < n) row_ptr[idx + 1] = off + pref[j];
        }
        __syncthreads();
    }
}

__global__ __launch_bounds__(256) void k_selfloop(const int* __restrict__ row_ptr, int* csr, int* cursor, int n) {
    int i = blockIdx.x * 256 + threadIdx.x;
    if (i < n) { int p = row_ptr[i]; csr[p] = i; cursor[i] = p + 1; }
}

__global__ __launch_bounds__(256) void k_scatter(const int* __restrict__ src, const int* __restrict__ dst,
                                                 int* cursor, int* csr, int e) {
    int i = blockIdx.x * 256 + threadIdx.x;
    if (i < e) { int p = atomicAdd(&cursor[dst[i]], 1); csr[p] = src[i]; }
}

__global__ __launch_bounds__(256) void k_bbounds(const int* __restrict__ bidx, int* bstart, int n) {
    int i = blockIdx.x * 256 + threadIdx.x;
    if (i < n) {
        int b = bidx[i];
        if (i == 0 || bidx[i - 1] != b) atomicMin(&bstart[b], i);
    }
}

__global__ void k_bfix(int* bstart, int n, int nb) {
    bstart[nb] = n;
    for (int b = nb - 1; b >= 0; --b)
        if (bstart[b] == n) bstart[b] = bstart[b + 1];
}

// round-nearest-even pack of two f32 into one uint (2×bf16, lo|hi<<16)
__device__ inline unsigned int bfpair(float lo, float hi) {
    unsigned int ul = __float_as_uint(lo); ul += 0x7fffu + ((ul >> 16) & 1u);
    unsigned int uh = __float_as_uint(hi); uh += 0x7fffu + ((uh >> 16) & 1u);
    return (ul >> 16) | (uh & 0xffff0000u);
}

// ---------------- fused GEMM + attention logits ----------------
// C[nrows x 128] = A[nrows x 128] @ W[128 x 128]; writes bf16-packed C (hb),
// vas[r] = C[r]·asrc, vad[r] = C[r]·adst.
// block: 256 threads, 64 rows; thread: 4 rows (ty*4) x 8 cols {tx*4+j, 64+tx*4+j}
__global__ __launch_bounds__(256) void k_gemm_fused(
    const float* __restrict__ A, const float* __restrict__ W,
    const float* __restrict__ asrc, const float* __restrict__ adst,
    unsigned int* __restrict__ hb, float* __restrict__ vas, float* __restrict__ vad,
    int nrows)
{
    __shared__ float Wl[128 * 128];
    int tid = threadIdx.x;
    for (int i = tid * 4; i < 128 * 128; i += 1024)
        *(float4*)&Wl[i] = *(const float4*)&W[i];
    __syncthreads();

    int tx = tid & 15, ty = tid >> 4;
    int row0 = blockIdx.x * 64 + ty * 4;
    const float* Ar[4];
#pragma unroll
    for (int r = 0; r < 4; ++r) Ar[r] = A + (size_t)min(row0 + r, nrows - 1) * 128;

    float acc[4][8];
#pragma unroll
    for (int r = 0; r < 4; ++r)
#pragma unroll
        for (int j = 0; j < 8; ++j) acc[r][j] = 0.f;

    for (int k0 = 0; k0 < 128; k0 += 4) {
        float4 a[4];
#pragma unroll
        for (int r = 0; r < 4; ++r) a[r] = *(const float4*)&Ar[r][k0];
#pragma unroll
        for (int kk = 0; kk < 4; ++kk) {
            float4 w0 = *(float4*)&Wl[(k0 + kk) * 128 + tx * 4];
            float4 w1 = *(float4*)&Wl[(k0 + kk) * 128 + 64 + tx * 4];
#pragma unroll
            for (int r = 0; r < 4; ++r) {
                float av = (&a[r].x)[kk];
                acc[r][0] = fmaf(av, w0.x, acc[r][0]);
                acc[r][1] = fmaf(av, w0.y, acc[r][1]);
                acc[r][2] = fmaf(av, w0.z, acc[r][2]);
                acc[r][3] = fmaf(av, w0.w, acc[r][3]);
                acc[r][4] = fmaf(av, w1.x, acc[r][4]);
                acc[r][5] = fmaf(av, w1.y, acc[r][5]);
                acc[r][6] = fmaf(av, w1.z, acc[r][6]);
                acc[r][7] = fmaf(av, w1.w, acc[r][7]);
            }
        }
    }

    float as0[8], ad0[8];
#pragma unroll
    for (int j = 0; j < 4; ++j) {
        as0[j]     = asrc[tx * 4 + j];
        as0[4 + j] = asrc[64 + tx * 4 + j];
        ad0[j]     = adst[tx * 4 + j];
        ad0[4 + j] = adst[64 + tx * 4 + j];
    }

#pragma unroll
    for (int r = 0; r < 4; ++r) {
        int row = row0 + r;
        float s = 0.f, d = 0.f;
#pragma unroll
        for (int j = 0; j < 8; ++j) { s = fmaf(acc[r][j], as0[j], s); d = fmaf(acc[r][j], ad0[j], d); }
#pragma unroll
        for (int o = 1; o < 16; o <<= 1) { s += __shfl_xor(s, o); d += __shfl_xor(d, o); }
        if (row < nrows) {
            if (tx == 0) { vas[row] = s; vad[row] = d; }
            uint2 p0, p1;
            p0.x = bfpair(acc[r][0], acc[r][1]); p0.y = bfpair(acc[r][2], acc[r][3]);
            p1.x = bfpair(acc[r][4], acc[r][5]); p1.y = bfpair(acc[r][6], acc[r][7]);
            *(uint2*)&hb[(size_t)row * 64 + tx * 2]      = p0;
            *(uint2*)&hb[(size_t)row * 64 + 32 + tx * 2] = p1;
        }
    }
}

// ---------------- aggregation: one wave per dst node, bf16 value gather ----------------
template <bool RELU>
__global__ __launch_bounds__(256) void k_agg(const unsigned int* __restrict__ hb,
                                             const float* __restrict__ vas,
                                             const float* __restrict__ vad,
                                             const int* __restrict__ row_ptr,
                                             const int* __restrict__ csr,
                                             const float* __restrict__ bias,
                                             float* __restrict__ out, int n) {
    int w = (blockIdx.x * 256 + threadIdx.x) >> 6;
    int lane = threadIdx.x & 63;
    if (w >= n) return;
    int beg = row_ptr[w], end = row_ptr[w + 1];
    float advl = vad[w];

    float m = -1e30f;
    for (int j = beg + lane; j < end; j += 64) {
        float e = vas[csr[j]] + advl;
        e = e > 0.f ? e : LEAKY * e;
        m = fmaxf(m, e);
    }
#pragma unroll
    for (int o = 32; o; o >>= 1) m = fmaxf(m, __shfl_xor(m, o));

    float z = 0.f;
    for (int j = beg + lane; j < end; j += 64) {
        float e = vas[csr[j]] + advl;
        e = e > 0.f ? e : LEAKY * e;
        z += __expf(e - m);
    }
#pragma unroll
    for (int o = 32; o; o >>= 1) z += __shfl_xor(z, o);
    float inv = 1.0f / z;

    // unnormalized accumulate (multiply by inv once at the end)
    float acc0 = 0.f, acc1 = 0.f;
    int j = beg;
    for (; j + 2 <= end; j += 2) {
        int s0 = csr[j], s1 = csr[j + 1];
        float e0 = vas[s0] + advl; e0 = e0 > 0.f ? e0 : LEAKY * e0;
        float e1 = vas[s1] + advl; e1 = e1 > 0.f ? e1 : LEAKY * e1;
        float w0 = __expf(e0 - m), w1 = __expf(e1 - m);
        unsigned int v0 = hb[(size_t)s0 * 64 + lane];
        unsigned int v1 = hb[(size_t)s1 * 64 + lane];
        acc0 = fmaf(w0, __uint_as_float(v0 << 16), acc0);
        acc1 = fmaf(w0, __uint_as_float(v0 & 0xffff0000u), acc1);
        acc0 = fmaf(w1, __uint_as_float(v1 << 16), acc0);
        acc1 = fmaf(w1, __uint_as_float(v1 & 0xffff0000u), acc1);
    }
    if (j < end) {
        int s0 = csr[j];
        float e0 = vas[s0] + advl; e0 = e0 > 0.f ? e0 : LEAKY * e0;
        float w0 = __expf(e0 - m);
        unsigned int v0 = hb[(size_t)s0 * 64 + lane];
        acc0 = fmaf(w0, __uint_as_float(v0 << 16), acc0);
        acc1 = fmaf(w0, __uint_as_float(v0 & 0xffff0000u), acc1);
    }

    float2 bv = *(const float2*)&bias[2 * lane];
    float o0 = fmaf(acc0, inv, bv.x);
    float o1 = fmaf(acc1, inv, bv.y);
    if (RELU) { o0 = fmaxf(o0, 0.f); o1 = fmaxf(o1, 0.f); }
    *(float2*)&out[(size_t)w * 128 + 2 * lane] = make_float2(o0, o1);
}

// ---------------- batch mean pool (batch_idx sorted) ----------------
__global__ __launch_bounds__(128) void k_pool(const float* __restrict__ h, const int* __restrict__ bstart,
                                              float* __restrict__ out, int t, int T) {
    int b = blockIdx.x;
    int chunk = blockIdx.y;
    int f = threadIdx.x;
    int s = bstart[b], e = bstart[b + 1];
    int cnt = e - s;
    if (cnt <= 0) return;
    int len = (cnt + 31) / 32;
    int cs = s + chunk * len;
    int ce = min(cs + len, e);
    if (cs >= ce) return;
    float acc = 0.f;
    for (int nidx = cs; nidx < ce; ++nidx) acc += h[(size_t)nidx * 128 + f];
    atomicAdd(&out[(size_t)(b * T + t) * 128 + f], acc / (float)cnt);
}

// ---------------- launch ----------------

extern "C" void kernel_launch(void* const* d_in, const int* in_sizes, int n_in,
                              void* d_out, int out_size, void* d_ws, size_t ws_size,
                              hipStream_t stream) {
    const float* x    = (const float*)d_in[0];
    const int*   ei   = (const int*)d_in[1];
    const int*   bidx = (const int*)d_in[2];
    const float* W1   = (const float*)d_in[3];
    const float* as1  = (const float*)d_in[4];
    const float* ad1  = (const float*)d_in[5];
    const float* b1   = (const float*)d_in[6];
    const float* W2   = (const float*)d_in[7];
    const float* as2  = (const float*)d_in[8];
    const float* ad2  = (const float*)d_in[9];
    const float* b2   = (const float*)d_in[10];
    float* out = (float*)d_out;

    const int E = in_sizes[1] / 2;
    const int N = in_sizes[2];
    const int T = in_sizes[0] / (N * 128);
    const int B = out_size / (T * 128);
    const int* src = ei;
    const int* dst = ei + E;

    char* wsp = (char*)d_ws;
    auto alloc = [&](size_t bytes) { void* p = wsp; wsp += (bytes + 255) / 256 * 256; return p; };
    float* F             = (float*)alloc((size_t)N * 128 * 4);   // f32 inter-layer buffer
    unsigned int* hb     = (unsigned int*)alloc((size_t)N * 64 * 4); // bf16-packed h
    float* vas           = (float*)alloc((size_t)N * 4);
    float* vad           = (float*)alloc((size_t)N * 4);
    int* row_ptr         = (int*)alloc((size_t)(N + 1) * 4);
    int* cnt             = (int*)alloc((size_t)N * 4);           // reused as scatter cursor
    int* csr             = (int*)alloc((size_t)(E + N) * 4);
    int* bstart          = (int*)alloc((size_t)(B + 2) * 4);

    hipMemsetAsync(d_out, 0, (size_t)out_size * sizeof(float), stream);

    int gN = (N + 255) / 256, gE = (E + 255) / 256;
    k_init<<<gN, 256, 0, stream>>>(cnt, bstart, N, B + 1);
    k_count<<<gE, 256, 0, stream>>>(dst, cnt, E);
    k_scan<<<1, 1024, 0, stream>>>(cnt, row_ptr, N);
    k_selfloop<<<gN, 256, 0, stream>>>(row_ptr, csr, cnt, N);
    k_scatter<<<gE, 256, 0, stream>>>(src, dst, cnt, csr, E);
    k_bbounds<<<gN, 256, 0, stream>>>(bidx, bstart, N);
    k_bfix<<<1, 1, 0, stream>>>(bstart, N, B);

    int gGemm = (N + 63) / 64;
    int gWave = (N + 3) / 4;  // 4 waves (nodes) per 256-thread block
    for (int t = 0; t < T; ++t) {
        const float* xt = x + (size_t)t * N * 128;
        k_gemm_fused<<<gGemm, 256, 0, stream>>>(xt, W1, as1, ad1, hb, vas, vad, N);
        k_agg<true><<<gWave, 256, 0, stream>>>(hb, vas, vad, row_ptr, csr, b1, F, N);
        k_gemm_fused<<<gGemm, 256, 0, stream>>>(F, W2, as2, ad2, hb, vas, vad, N);
        k_agg<false><<<gWave, 256, 0, stream>>>(hb, vas, vad, row_ptr, csr, b2, F, N);
        k_pool<<<dim3(B, 32), 128, 0, stream>>>(F, bstart, out, t, T);
    }
}

// Round 4
// 857.963 us; speedup vs baseline: 1.6550x; 1.2827x over previous
//
#include <hip/hip_runtime.h>
#include <hip/hip_bf16.h>

#define LEAKY 0.2f

// ---------------- CSR build ----------------

__global__ __launch_bounds__(256) void k_init(int* cnt, int* bstart, int n, int nb) {
    int i = blockIdx.x * 256 + threadIdx.x;
    if (i < n) cnt[i] = 1;            // self-loop pre-counted
    if (i < nb) bstart[i] = n;        // batch-boundary init
}

__global__ __launch_bounds__(256) void k_count(const int* __restrict__ dst, int* cnt, int e) {
    int i = blockIdx.x * 256 + threadIdx.x;
    if (i < e) atomicAdd(&cnt[dst[i]], 1);
}

// single-block scan: 8 elems/thread, wave shfl scan, cross-wave via LDS
__global__ __launch_bounds__(1024) void k_scan(const int* __restrict__ cnt, int* row_ptr, int n) {
    __shared__ int wsum[17];
    int tid = threadIdx.x, lane = tid & 63, wid = tid >> 6;
    if (tid == 0) { wsum[16] = 0; row_ptr[0] = 0; }
    __syncthreads();
    for (int base = 0; base < n; base += 8192) {
        int i0 = base + tid * 8;
        int v, p = 0, pref[8];
#pragma unroll
        for (int j = 0; j < 8; ++j) {
            int idx = i0 + j;
            v = (idx < n) ? cnt[idx] : 0;
            p += v; pref[j] = p;
        }
        int sc = p;
#pragma unroll
        for (int o = 1; o < 64; o <<= 1) { int t = __shfl_up(sc, o); if (lane >= o) sc += t; }
        if (lane == 63) wsum[wid] = sc;
        __syncthreads();
        if (tid == 0) {
            int run = wsum[16];
            for (int ww = 0; ww < 16; ++ww) { int tt = wsum[ww]; wsum[ww] = run; run += tt; }
            wsum[16] = run;
        }
        __syncthreads();
        int off = wsum[wid] + (sc - p);
#pragma unroll
        for (int j = 0; j < 8; ++j) {
            int idx = i0 + j;
            if (idx < n) row_ptr[idx + 1] = off + pref[j];
        }
        __syncthreads();
    }
}

__global__ __launch_bounds__(256) void k_selfloop(const int* __restrict__ row_ptr, int* csr, int* cursor, int n) {
    int i = blockIdx.x * 256 + threadIdx.x;
    if (i < n) { int p = row_ptr[i]; csr[p] = i; cursor[i] = p + 1; }
}

__global__ __launch_bounds__(256) void k_scatter(const int* __restrict__ src, const int* __restrict__ dst,
                                                 int* cursor, int* csr, int e) {
    int i = blockIdx.x * 256 + threadIdx.x;
    if (i < e) { int p = atomicAdd(&cursor[dst[i]], 1); csr[p] = src[i]; }
}

__global__ __launch_bounds__(256) void k_bbounds(const int* __restrict__ bidx, int* bstart, int n) {
    int i = blockIdx.x * 256 + threadIdx.x;
    if (i < n) {
        int b = bidx[i];
        if (i == 0 || bidx[i - 1] != b) atomicMin(&bstart[b], i);
    }
}

__global__ void k_bfix(int* bstart, int n, int nb) {
    bstart[nb] = n;
    for (int b = nb - 1; b >= 0; --b)
        if (bstart[b] == n) bstart[b] = bstart[b + 1];
}

// round-nearest-even pack of two f32 into one uint (2×bf16, lo|hi<<16)
__device__ inline unsigned int bfpair(float lo, float hi) {
    unsigned int ul = __float_as_uint(lo); ul += 0x7fffu + ((ul >> 16) & 1u);
    unsigned int uh = __float_as_uint(hi); uh += 0x7fffu + ((uh >> 16) & 1u);
    return (ul >> 16) | (uh & 0xffff0000u);
}

// ---------------- fused GEMM + attention logits ----------------
// C[nrows x 128] = A[nrows x 128] @ W[128 x 128]; writes bf16-packed C (hb),
// vas[r] = C[r]·asrc, vad[r] = C[r]·adst.
// block: 256 threads, 128 rows; thread: 8 rows (ty*8) x 8 cols {tx*4+j, 64+tx*4+j}
// A loads are register double-buffered (a1 prefetch covers L1/L2 latency under FMAs).
__global__ __launch_bounds__(256) void k_gemm_fused(
    const float* __restrict__ A, const float* __restrict__ W,
    const float* __restrict__ asrc, const float* __restrict__ adst,
    unsigned int* __restrict__ hb, float* __restrict__ vas, float* __restrict__ vad,
    int nrows)
{
    __shared__ float Wl[128 * 128];
    int tid = threadIdx.x;
#pragma unroll
    for (int i = 0; i < 16; ++i)
        *(float4*)&Wl[tid * 4 + i * 1024] = *(const float4*)&W[tid * 4 + i * 1024];
    __syncthreads();

    int tx = tid & 15, ty = tid >> 4;
    int row0 = blockIdx.x * 128 + ty * 8;
    const char* baseA = (const char*)A;
    int offs[8];
#pragma unroll
    for (int r = 0; r < 8; ++r) offs[r] = min(row0 + r, nrows - 1) * 512;  // byte offset of row

    float acc[8][8];
#pragma unroll
    for (int r = 0; r < 8; ++r)
#pragma unroll
        for (int j = 0; j < 8; ++j) acc[r][j] = 0.f;

    float4 a0[8], a1[8];
#pragma unroll
    for (int r = 0; r < 8; ++r) a0[r] = *(const float4*)(baseA + offs[r]);

#define FMA_BLOCK(KB)                                                          \
    {                                                                          \
        _Pragma("unroll") for (int kk = 0; kk < 4; ++kk) {                     \
            float4 w0 = *(float4*)&Wl[(KB + kk) * 128 + tx * 4];               \
            float4 w1 = *(float4*)&Wl[(KB + kk) * 128 + 64 + tx * 4];          \
            _Pragma("unroll") for (int r = 0; r < 8; ++r) {                    \
                float av = (&a0[r].x)[kk];                                     \
                acc[r][0] = fmaf(av, w0.x, acc[r][0]);                         \
                acc[r][1] = fmaf(av, w0.y, acc[r][1]);                         \
                acc[r][2] = fmaf(av, w0.z, acc[r][2]);                         \
                acc[r][3] = fmaf(av, w0.w, acc[r][3]);                         \
                acc[r][4] = fmaf(av, w1.x, acc[r][4]);                         \
                acc[r][5] = fmaf(av, w1.y, acc[r][5]);                         \
                acc[r][6] = fmaf(av, w1.z, acc[r][6]);                         \
                acc[r][7] = fmaf(av, w1.w, acc[r][7]);                         \
            }                                                                  \
        }                                                                      \
    }

    for (int k0 = 0; k0 < 124; k0 += 4) {
#pragma unroll
        for (int r = 0; r < 8; ++r) a1[r] = *(const float4*)(baseA + offs[r] + (k0 + 4) * 4);
        FMA_BLOCK(k0)
#pragma unroll
        for (int r = 0; r < 8; ++r) a0[r] = a1[r];
    }
    FMA_BLOCK(124)
#undef FMA_BLOCK

    float as0[8], ad0[8];
#pragma unroll
    for (int j = 0; j < 4; ++j) {
        as0[j]     = asrc[tx * 4 + j];
        as0[4 + j] = asrc[64 + tx * 4 + j];
        ad0[j]     = adst[tx * 4 + j];
        ad0[4 + j] = adst[64 + tx * 4 + j];
    }

#pragma unroll
    for (int r = 0; r < 8; ++r) {
        int row = row0 + r;
        float s = 0.f, d = 0.f;
#pragma unroll
        for (int j = 0; j < 8; ++j) { s = fmaf(acc[r][j], as0[j], s); d = fmaf(acc[r][j], ad0[j], d); }
#pragma unroll
        for (int o = 1; o < 16; o <<= 1) { s += __shfl_xor(s, o); d += __shfl_xor(d, o); }
        if (row < nrows) {
            if (tx == 0) { vas[row] = s; vad[row] = d; }
            uint2 p0, p1;
            p0.x = bfpair(acc[r][0], acc[r][1]); p0.y = bfpair(acc[r][2], acc[r][3]);
            p1.x = bfpair(acc[r][4], acc[r][5]); p1.y = bfpair(acc[r][6], acc[r][7]);
            *(uint2*)&hb[(size_t)row * 64 + tx * 2]      = p0;
            *(uint2*)&hb[(size_t)row * 64 + 32 + tx * 2] = p1;
        }
    }
}

// ---------------- aggregation: one wave per dst node ----------------
// m/z phases: 64-lane parallel over edges. Value phase: 4 edge-groups x 16 lanes,
// each lane gathers uint4 (8 bf16 feats) -> 4-8 rows in flight per wave.
template <bool RELU>
__global__ __launch_bounds__(256) void k_agg(const unsigned int* __restrict__ hb,
                                             const float* __restrict__ vas,
                                             const float* __restrict__ vad,
                                             const int* __restrict__ row_ptr,
                                             const int* __restrict__ csr,
                                             const float* __restrict__ bias,
                                             float* __restrict__ out, int n) {
    int w = (blockIdx.x * 256 + threadIdx.x) >> 6;
    int lane = threadIdx.x & 63;
    if (w >= n) return;
    int beg = row_ptr[w], end = row_ptr[w + 1];
    float advl = vad[w];

    float m = -1e30f;
    for (int j = beg + lane; j < end; j += 64) {
        float e = vas[csr[j]] + advl;
        e = e > 0.f ? e : LEAKY * e;
        m = fmaxf(m, e);
    }
#pragma unroll
    for (int o = 32; o; o >>= 1) m = fmaxf(m, __shfl_xor(m, o));

    float z = 0.f;
    for (int j = beg + lane; j < end; j += 64) {
        float e = vas[csr[j]] + advl;
        e = e > 0.f ? e : LEAKY * e;
        z += __expf(e - m);
    }
#pragma unroll
    for (int o = 32; o; o >>= 1) z += __shfl_xor(z, o);
    float inv = 1.0f / z;

    int g = lane >> 4, l = lane & 15;
    float acc[8];
#pragma unroll
    for (int i = 0; i < 8; ++i) acc[i] = 0.f;

#define ACC_EDGE(S, WGT, V)                                                    \
    {                                                                          \
        acc[0] = fmaf(WGT, __uint_as_float(V.x << 16), acc[0]);                \
        acc[1] = fmaf(WGT, __uint_as_float(V.x & 0xffff0000u), acc[1]);        \
        acc[2] = fmaf(WGT, __uint_as_float(V.y << 16), acc[2]);                \
        acc[3] = fmaf(WGT, __uint_as_float(V.y & 0xffff0000u), acc[3]);        \
        acc[4] = fmaf(WGT, __uint_as_float(V.z << 16), acc[4]);                \
        acc[5] = fmaf(WGT, __uint_as_float(V.z & 0xffff0000u), acc[5]);        \
        acc[6] = fmaf(WGT, __uint_as_float(V.w << 16), acc[6]);                \
        acc[7] = fmaf(WGT, __uint_as_float(V.w & 0xffff0000u), acc[7]);        \
    }

    int j = beg + g;
    for (; j + 4 < end; j += 8) {  // two edges per group in flight
        int s0 = csr[j], s1 = csr[j + 4];
        float e0 = vas[s0] + advl; e0 = e0 > 0.f ? e0 : LEAKY * e0;
        float e1 = vas[s1] + advl; e1 = e1 > 0.f ? e1 : LEAKY * e1;
        float w0 = __expf(e0 - m), w1 = __expf(e1 - m);
        uint4 v0 = *(const uint4*)&hb[(size_t)s0 * 64 + l * 4];
        uint4 v1 = *(const uint4*)&hb[(size_t)s1 * 64 + l * 4];
        ACC_EDGE(s0, w0, v0)
        ACC_EDGE(s1, w1, v1)
    }
    if (j < end) {
        int s0 = csr[j];
        float e0 = vas[s0] + advl; e0 = e0 > 0.f ? e0 : LEAKY * e0;
        float w0 = __expf(e0 - m);
        uint4 v0 = *(const uint4*)&hb[(size_t)s0 * 64 + l * 4];
        ACC_EDGE(s0, w0, v0)
    }
#undef ACC_EDGE

#pragma unroll
    for (int i = 0; i < 8; ++i) {
        acc[i] += __shfl_xor(acc[i], 16);
        acc[i] += __shfl_xor(acc[i], 32);
    }

    if (lane < 16) {
        float4 b0 = *(const float4*)&bias[l * 8];
        float4 b1 = *(const float4*)&bias[l * 8 + 4];
        float4 o0 = make_float4(fmaf(acc[0], inv, b0.x), fmaf(acc[1], inv, b0.y),
                                fmaf(acc[2], inv, b0.z), fmaf(acc[3], inv, b0.w));
        float4 o1 = make_float4(fmaf(acc[4], inv, b1.x), fmaf(acc[5], inv, b1.y),
                                fmaf(acc[6], inv, b1.z), fmaf(acc[7], inv, b1.w));
        if (RELU) {
            o0.x = fmaxf(o0.x, 0.f); o0.y = fmaxf(o0.y, 0.f); o0.z = fmaxf(o0.z, 0.f); o0.w = fmaxf(o0.w, 0.f);
            o1.x = fmaxf(o1.x, 0.f); o1.y = fmaxf(o1.y, 0.f); o1.z = fmaxf(o1.z, 0.f); o1.w = fmaxf(o1.w, 0.f);
        }
        *(float4*)&out[(size_t)w * 128 + l * 8]     = o0;
        *(float4*)&out[(size_t)w * 128 + l * 8 + 4] = o1;
    }
}

// ---------------- batch mean pool (batch_idx sorted) ----------------
__global__ __launch_bounds__(128) void k_pool(const float* __restrict__ h, const int* __restrict__ bstart,
                                              float* __restrict__ out, int t, int T) {
    int b = blockIdx.x;
    int chunk = blockIdx.y;
    int f = threadIdx.x;
    int s = bstart[b], e = bstart[b + 1];
    int cnt = e - s;
    if (cnt <= 0) return;
    int len = (cnt + 31) / 32;
    int cs = s + chunk * len;
    int ce = min(cs + len, e);
    if (cs >= ce) return;
    float acc = 0.f;
    for (int nidx = cs; nidx < ce; ++nidx) acc += h[(size_t)nidx * 128 + f];
    atomicAdd(&out[(size_t)(b * T + t) * 128 + f], acc / (float)cnt);
}

// ---------------- launch ----------------

extern "C" void kernel_launch(void* const* d_in, const int* in_sizes, int n_in,
                              void* d_out, int out_size, void* d_ws, size_t ws_size,
                              hipStream_t stream) {
    const float* x    = (const float*)d_in[0];
    const int*   ei   = (const int*)d_in[1];
    const int*   bidx = (const int*)d_in[2];
    const float* W1   = (const float*)d_in[3];
    const float* as1  = (const float*)d_in[4];
    const float* ad1  = (const float*)d_in[5];
    const float* b1   = (const float*)d_in[6];
    const float* W2   = (const float*)d_in[7];
    const float* as2  = (const float*)d_in[8];
    const float* ad2  = (const float*)d_in[9];
    const float* b2   = (const float*)d_in[10];
    float* out = (float*)d_out;

    const int E = in_sizes[1] / 2;
    const int N = in_sizes[2];
    const int T = in_sizes[0] / (N * 128);
    const int B = out_size / (T * 128);
    const int* src = ei;
    const int* dst = ei + E;

    char* wsp = (char*)d_ws;
    auto alloc = [&](size_t bytes) { void* p = wsp; wsp += (bytes + 255) / 256 * 256; return p; };
    float* F             = (float*)alloc((size_t)N * 128 * 4);       // f32 inter-layer buffer
    unsigned int* hb     = (unsigned int*)alloc((size_t)N * 64 * 4); // bf16-packed h
    float* vas           = (float*)alloc((size_t)N * 4);
    float* vad           = (float*)alloc((size_t)N * 4);
    int* row_ptr         = (int*)alloc((size_t)(N + 1) * 4);
    int* cnt             = (int*)alloc((size_t)N * 4);               // reused as scatter cursor
    int* csr             = (int*)alloc((size_t)(E + N) * 4);
    int* bstart          = (int*)alloc((size_t)(B + 2) * 4);

    hipMemsetAsync(d_out, 0, (size_t)out_size * sizeof(float), stream);

    int gN = (N + 255) / 256, gE = (E + 255) / 256;
    k_init<<<gN, 256, 0, stream>>>(cnt, bstart, N, B + 1);
    k_count<<<gE, 256, 0, stream>>>(dst, cnt, E);
    k_scan<<<1, 1024, 0, stream>>>(cnt, row_ptr, N);
    k_selfloop<<<gN, 256, 0, stream>>>(row_ptr, csr, cnt, N);
    k_scatter<<<gE, 256, 0, stream>>>(src, dst, cnt, csr, E);
    k_bbounds<<<gN, 256, 0, stream>>>(bidx, bstart, N);
    k_bfix<<<1, 1, 0, stream>>>(bstart, N, B);

    int gGemm = (N + 127) / 128;
    int gWave = (N + 3) / 4;  // 4 waves (nodes) per 256-thread block
    for (int t = 0; t < T; ++t) {
        const float* xt = x + (size_t)t * N * 128;
        k_gemm_fused<<<gGemm, 256, 0, stream>>>(xt, W1, as1, ad1, hb, vas, vad, N);
        k_agg<true><<<gWave, 256, 0, stream>>>(hb, vas, vad, row_ptr, csr, b1, F, N);
        k_gemm_fused<<<gGemm, 256, 0, stream>>>(F, W2, as2, ad2, hb, vas, vad, N);
        k_agg<false><<<gWave, 256, 0, stream>>>(hb, vas, vad, row_ptr, csr, b2, F, N);
        k_pool<<<dim3(B, 32), 128, 0, stream>>>(F, bstart, out, t, T);
    }
}